// Round 16
// baseline (649.908 us; speedup 1.0000x reference)
//
#include <hip/hip_runtime.h>
#include <hip/hip_cooperative_groups.h>
#include <math.h>

namespace cg = cooperative_groups;

#define NN 100000
#define NE 1600000
#define NT (NE + NN)   // 1700000 edges incl. self-loops
#define DD 128
#define NB 500          // dst buckets
#define BR 200          // node range per bucket (NB*BR == NN)
#define BCAP 4096       // bucket capacity (mean 3200, sigma 56 -> 15.9 sigma headroom)
#define NCH 2048        // edges per bucket-sort block
#define NBK 782         // ceil(NE/NCH); also the cooperative grid size
#define NBG 1563        // ceil(NN/64) gemm blocks
#define PW 68           // padded LDS row stride in uints (64 + 4 -> 2-way banks only)
#define BMAGIC 21474837u // ceil(2^32/200); exact for d < 100000

typedef unsigned int uint;
typedef unsigned short ushort;
typedef __attribute__((ext_vector_type(8))) short bf16x8;
typedef __attribute__((ext_vector_type(4))) float f32x4;

// round-to-nearest-even fp32 -> bf16 (16-bit payload in a uint)
__device__ __forceinline__ uint bfr(float f){
  uint u = __float_as_uint(f);
  return (u + 0x7FFFu + ((u >> 16) & 1u)) >> 16;
}
__device__ __forceinline__ uint pk2(float a, float b){
  return (bfr(a) & 0xFFFFu) | (bfr(b) << 16);
}
__device__ __forceinline__ bf16x8 asbf(uint4 u){
  union { uint4 u; bf16x8 b; } c; c.u = u; return c.b;
}

// ---------------- cooperative preprocessing: init -> bucket -> scan/deg -> build ----------------
// 782 blocks x 256 thr, 18.4KB LDS -> 8 blocks/CU capacity (3.05 needed: all resident).
// grid.sync() between phases replaces 3 kernel launches. R14 numerics preserved.
__global__ __launch_bounds__(256) void k_pre(const float* __restrict__ W1f, const float* __restrict__ W2f,
    uint* __restrict__ Wt1, uint* __restrict__ Wt2,
    const int* __restrict__ ei, int* __restrict__ gcnt, uint* __restrict__ bedge,
    int* __restrict__ bbase, int* __restrict__ deg, float* __restrict__ dis,
    int* __restrict__ rowptr, uint* __restrict__ es){
  __shared__ uint smem[4608];              // bucket: ent|bbs|hist|fl|gb = 4572 uints
  cg::grid_group grid = cg::this_grid();
  int t = threadIdx.x;
  int blk = blockIdx.x;

  // ---- phase 0: Wt transposes (blocks 0,1) + gcnt zero (blocks 2..33) ----
  if (blk < 2){
    const float* W = blk ? W2f : W1f;
    uint* Wt = blk ? Wt2 : Wt1;
    int n = t >> 1, k0 = (t & 1) * 64;
    for (int kk = 0; kk < 64; kk += 2){
      float v0 = W[(size_t)(k0+kk  )*DD + n];
      float v1 = W[(size_t)(k0+kk+1)*DD + n];
      Wt[(size_t)n*64 + ((k0+kk)>>1)] = pk2(v0, v1);
    }
  } else if (blk < 34){
    int i = (blk - 2)*256 + t;
    if (i < 8000) gcnt[i] = 0;
  }
  __threadfence();
  grid.sync();

  // ---- phase 1: bucket sort (all 782 blocks) ----
  {
    uint*   ent  = smem;                   // 2048 uints
    ushort* bbs  = (ushort*)(smem + NCH);  // 2048 ushorts
    int*    hist = (int*)(smem + NCH + NCH/2);
    int*    fl   = hist + NB;
    int*    gb   = fl + NB;
    int base = blk * NCH;
    int nv = NE - base; if (nv > NCH) nv = NCH;
    for (int b = t; b < NB; b += 256){ hist[b] = 0; fl[b] = 0; }
    __syncthreads();
    for (int j = t; j < nv; j += 256){
      int i = base + j;                    // coalesced
      uint s = (uint)ei[i];
      uint d = (uint)ei[NE + i];
      uint b = __umulhi(d, BMAGIC);        // d / 200
      uint dl = d - b*BR;
      ent[j] = s | (dl << 17);
      bbs[j] = (ushort)b;
      atomicAdd(&hist[b], 1);
    }
    __syncthreads();
    for (int b = t; b < NB; b += 256){
      int h = hist[b];
      gb[b] = h ? atomicAdd(&gcnt[b*16], h) : 0;   // bulk reservation
    }
    __syncthreads();
    for (int j = t; j < nv; j += 256){
      uint b = bbs[j];
      int q = atomicAdd(&fl[b], 1);        // LDS fill
      bedge[(size_t)b*BCAP + gb[b] + q] = ent[j];
    }
  }
  __threadfence();
  grid.sync();

  // ---- phase 2: bucket-total scan (block 0) | degree -> deg,dis (blocks 1..500) ----
  if (blk == 0){
    int* sm = (int*)smem;
    int i0 = 2*t, i1 = 2*t + 1;
    int v0 = (i0 < NB) ? (gcnt[i0*16] + BR) : 0;
    int v1 = (i1 < NB) ? (gcnt[i1*16] + BR) : 0;
    int p = v0 + v1;
    sm[t] = p;
    __syncthreads();
    for (int off = 1; off < 256; off <<= 1){
      int a = (t >= off) ? sm[t-off] : 0;
      __syncthreads();
      sm[t] += a;
      __syncthreads();
    }
    int excl = sm[t] - p;
    if (i0 < NB) bbase[i0] = excl;
    if (i1 < NB) bbase[i1] = excl + v0;
  } else if (blk <= NB){
    int b = blk - 1;
    int* cl = (int*)smem;                  // BR ints
    if (t < BR) cl[t] = 0;
    __syncthreads();
    int cnt = gcnt[b*16];
    for (int e = t; e < cnt; e += 256){
      atomicAdd(&cl[bedge[(size_t)b*BCAP + e] >> 17], 1);
    }
    __syncthreads();
    if (t < BR){
      int n = b*BR + t;
      int dg = cl[t];
      deg[n] = dg;                         // in-degree excl self-loop
      dis[n] = rsqrtf((float)(dg + 1));
    }
  }
  __threadfence();
  grid.sync();

  // ---- phase 3: CSR build (blocks 0..499); es = plain src, rowptr monotone ----
  if (blk < NB){
    int b = blk;
    int base = bbase[b];
    int* cl = (int*)smem;
    int* fl = cl + BR;
    int* pf = cl + 2*BR;                   // 256 ints
    if (t < BR){ cl[t] = deg[b*BR + t]; fl[t] = 0; }
    __syncthreads();
    // inclusive scan over (cl[i]+1)
    int v = (t < BR) ? (cl[t] + 1) : 0;
    pf[t] = v;
    __syncthreads();
    for (int off = 1; off < 256; off <<= 1){
      int a = (t >= off) ? pf[t-off] : 0;
      __syncthreads();
      pf[t] += a;
      __syncthreads();
    }
    if (t < BR){
      int n  = b*BR + t;
      int p0 = base + pf[t] - v;           // exclusive prefix (globally monotone)
      rowptr[n] = p0;
      es[p0 + cl[t]] = (uint)n;            // self-loop last
    }
    if (b == NB-1 && t == 0) rowptr[NN] = NT;
    __syncthreads();
    int cnt = gcnt[b*16];
    for (int e = t; e < cnt; e += 256){
      uint u = bedge[(size_t)b*BCAP + e];
      int  dloc = u >> 17;
      int  q  = atomicAdd(&fl[dloc], 1);
      int  p0 = base + pf[dloc] - (cl[dloc] + 1);
      es[p0 + q] = u & 0x1FFFFu;
    }
  }
}

// ---------------- shared GEMM body: Y[r] = bf16(dis[r] * (X@W)[r]) ----------------
// 64 rows/block. Staging coalesced into padded LDS (2-way banks only);
// fragments via ds_read_b128; lane (g,li): Wt row nt*16+li, X row wv*16+li,
// k-chunk ks*32+g*8. C/D: lane owns row r, cols nt*16+g*4+reg (HW-verified).
template<int IN_BF16>
__device__ __forceinline__ void gemm_body(uint* __restrict__ Ws, uint* __restrict__ Xs,
    const void* __restrict__ Xv, const uint* __restrict__ Wt,
    const float* __restrict__ dis, uint* __restrict__ Y, int row0){
  int t = threadIdx.x;
  // stage Wt: 2048 uint4, coalesced
  #pragma unroll
  for (int it = 0; it < 8; ++it){
    int f = it*256 + t;
    uint4 v = ((const uint4*)Wt)[f];
    int row = f >> 4, c4 = f & 15;
    *(uint4*)&Ws[row*PW + c4*4] = v;
  }
  // stage X tile (64 rows), coalesced; zero-fill invalid rows
  if (!IN_BF16){
    const float* X = (const float*)Xv;
    #pragma unroll
    for (int it = 0; it < 8; ++it){
      int f = it*256 + t;                  // 0..2047 float4
      int row = f >> 5, c4 = f & 31;
      int gr = row0 + row;
      float4 v = (gr < NN) ? ((const float4*)X)[(size_t)gr*32 + c4]
                           : make_float4(0.f,0.f,0.f,0.f);
      uint2 p; p.x = pk2(v.x, v.y); p.y = pk2(v.z, v.w);
      *(uint2*)&Xs[row*PW + c4*2] = p;
    }
  } else {
    const uint* X = (const uint*)Xv;
    #pragma unroll
    for (int it = 0; it < 4; ++it){
      int f = it*256 + t;                  // 0..1023 uint4
      int row = f >> 4, c4 = f & 15;
      int gr = row0 + row;
      uint4 v = (gr < NN) ? ((const uint4*)X)[(size_t)gr*16 + c4]
                          : make_uint4(0,0,0,0);
      *(uint4*)&Xs[row*PW + c4*4] = v;
    }
  }
  __syncthreads();

  int wv = t >> 6, l = t & 63;
  int g = l >> 4, li = l & 15;
  int rb = wv*16 + li;                    // row within block
  int r  = row0 + rb;
  f32x4 acc[8];
  #pragma unroll
  for (int i = 0; i < 8; ++i) acc[i] = (f32x4){0.f,0.f,0.f,0.f};

  #pragma unroll
  for (int ks = 0; ks < 4; ++ks){
    int c = (ks*4 + g)*4;                 // uint offset of this lane's k-chunk
    bf16x8 bfrag = asbf(*(const uint4*)&Xs[rb*PW + c]);
    #pragma unroll
    for (int nt = 0; nt < 8; ++nt){
      bf16x8 afrag = asbf(*(const uint4*)&Ws[(nt*16 + li)*PW + c]);
      acc[nt] = __builtin_amdgcn_mfma_f32_16x16x32_bf16(afrag, bfrag, acc[nt], 0, 0, 0);
    }
  }
  if (r < NN){
    float dr = dis[r];
    #pragma unroll
    for (int nt = 0; nt < 8; ++nt){
      uint2 o;
      o.x = pk2(acc[nt][0]*dr, acc[nt][1]*dr);
      o.y = pk2(acc[nt][2]*dr, acc[nt][3]*dr);
      *(uint2*)&Y[(size_t)r*64 + nt*8 + g*2] = o;   // row-major packed
    }
  }
}

__global__ __launch_bounds__(256, 3) void k_gemm1(const float* __restrict__ X,
    const uint* __restrict__ Wt, const float* __restrict__ dis, uint* __restrict__ Y){
  __shared__ uint smem[192*PW];
  gemm_body<0>(smem, smem + 128*PW, X, Wt, dis, Y, blockIdx.x*64);
}

__global__ __launch_bounds__(256, 3) void k_gemm2(const uint* __restrict__ X,
    const uint* __restrict__ Wt, const float* __restrict__ dis, uint* __restrict__ Y){
  __shared__ uint smem[192*PW];
  gemm_body<1>(smem, smem + 128*PW, X, Wt, dis, Y, blockIdx.x*64);
}

// ---------------- CSR aggregation + bias + ELU (flat, R9-proven) ----------------
// out[n] = elu(dis[n] * sum_{s in N(n)} H'[s] + b); H' rows pre-scaled by dis[s].
// one WAVE per node (4 nodes / 256-thread block); lane = bf16 channel pair;
// 16x edge unroll -> 16 gathers in flight per wave.
template<int OUT_BF16>
__global__ __launch_bounds__(256) void k_agg(const uint* __restrict__ H,
    const int* __restrict__ rowptr, const float* __restrict__ dis,
    const uint* __restrict__ es, const float* __restrict__ bias,
    void* __restrict__ outv){
  int wid  = threadIdx.x >> 6;
  int lane = threadIdx.x & 63;
  int n = blockIdx.x*4 + wid;            // grid*4 == NN exactly
  int e0 = rowptr[n];
  int e1 = rowptr[n+1];
  float a0 = 0.f, a1 = 0.f, a2 = 0.f, a3 = 0.f;
  int e = e0;

#define ASTEP(k,A,B) { uint s##k = es[e+k]; \
    uint h##k = H[(size_t)s##k*64 + lane]; \
    A += __uint_as_float(h##k << 16); \
    B += __uint_as_float(h##k & 0xFFFF0000u); }

  for (; e + 16 <= e1; e += 16){
    ASTEP( 0,a0,a1) ASTEP( 1,a2,a3) ASTEP( 2,a0,a1) ASTEP( 3,a2,a3)
    ASTEP( 4,a0,a1) ASTEP( 5,a2,a3) ASTEP( 6,a0,a1) ASTEP( 7,a2,a3)
    ASTEP( 8,a0,a1) ASTEP( 9,a2,a3) ASTEP(10,a0,a1) ASTEP(11,a2,a3)
    ASTEP(12,a0,a1) ASTEP(13,a2,a3) ASTEP(14,a0,a1) ASTEP(15,a2,a3)
  }
  for (; e + 4 <= e1; e += 4){
    ASTEP(0,a0,a1) ASTEP(1,a2,a3) ASTEP(2,a0,a1) ASTEP(3,a2,a3)
  }
  for (; e < e1; ++e){
    ASTEP(0,a0,a1)
  }
#undef ASTEP

  float dn = dis[n];
  float2 b = *(const float2*)&bias[lane*2];
  float v0 = fmaf(dn, a0 + a2, b.x);
  float v1 = fmaf(dn, a1 + a3, b.y);
  v0 = (v0 > 0.f) ? v0 : expm1f(v0);
  v1 = (v1 > 0.f) ? v1 : expm1f(v1);
  if (OUT_BF16){
    ((uint*)outv)[(size_t)n*64 + lane] = pk2(v0, v1);
  } else {
    float2 o; o.x = v0; o.y = v1;
    *(float2*)&((float*)outv)[(size_t)n*DD + lane*2] = o;
  }
}

// ---------------- launch ----------------

extern "C" void kernel_launch(void* const* d_in, const int* in_sizes, int n_in,
                              void* d_out, int out_size, void* d_ws, size_t ws_size,
                              hipStream_t stream){
  const float* x  = (const float*)d_in[0];
  const int*   ei = (const int*)d_in[1];   // [2, NE]: src row then dst row
  const float* W1 = (const float*)d_in[2];
  const float* b1 = (const float*)d_in[3];
  const float* W2 = (const float*)d_in[4];
  const float* b2 = (const float*)d_in[5];

  // workspace carve-up (int units), every region 64-int (256B) aligned.
  // H alignment CRITICAL (misaligned 256B rows -> +42% gather FETCH, R4..R8).
  // out1 = FULL 6.4M uints (R11 lesson); aliases bedge (dead after k_pre) --
  // safe: agg<1> (only out1 writer) runs after k_pre. H2 = H (dead after agg<1>).
  int*   ws_i   = (int*)d_ws;
  int*   gcnt   = ws_i + 0;                 // [0, 8000)  500*16 padded counters
  int*   bbase  = ws_i + 8000;              // [8000, 8576)
  float* dis    = (float*)(ws_i + 8576);    // [8576, 108608)
  int*   rowptr = ws_i + 108608;            // [108608, 208704)  100001 used
  int*   deg    = ws_i + 208704;            // [208704, 308736)
  uint*  Wt1    = (uint*)(ws_i + 308736);   // [308736, 316928)  128x128 bf16
  uint*  Wt2    = (uint*)(ws_i + 316928);   // [316928, 325120)
  uint*  es     = (uint*)(ws_i + 325120);   // [325120, 2025152)  1700000 used
  uint*  bedge  = (uint*)(ws_i + 2025152);  // [2025152, 4073152)  dead after k_pre
  uint*  out1   = (uint*)(ws_i + 2025152);  // [2025152, 8425152)  6.4M uints, %256==0
  uint*  H      = (uint*)(ws_i + 8425152);  // [8425152, 14825152) 6.4M uints, %256==0
  uint*  H2     = H;                        //   reused: H dead after agg<1>
  // total 14825152 ints = 59.3 MB (proven fits, R14)

  // cooperative pre-chain: init -> bucket -> scan/deg -> build (3 grid syncs)
  void* args[] = {(void*)&W1, (void*)&W2, (void*)&Wt1, (void*)&Wt2,
                  (void*)&ei, (void*)&gcnt, (void*)&bedge,
                  (void*)&bbase, (void*)&deg, (void*)&dis,
                  (void*)&rowptr, (void*)&es};
  hipLaunchCooperativeKernel((void*)k_pre, dim3(NBK), dim3(256), args, 0, stream);

  // layer 1: H = bf16(dis*(x@W1)) ; out1 = bf16(elu(dis*agg + b1))
  k_gemm1 <<<NBG,   256, 0, stream>>>(x, Wt1, dis, H);
  k_agg<1><<<25000, 256, 0, stream>>>(H, rowptr, dis, es, b1, out1);
  // layer 2: H2 = bf16(dis*(out1@W2)) ; out = elu(dis*agg + b2)
  k_gemm2 <<<NBG,   256, 0, stream>>>(out1, Wt2, dis, H2);
  k_agg<0><<<25000, 256, 0, stream>>>(H2, rowptr, dis, es, b2, d_out);
}

// Round 17
// 233.655 us; speedup vs baseline: 2.7815x; 2.7815x over previous
//
#include <hip/hip_runtime.h>
#include <math.h>

#define NN 100000
#define NE 1600000
#define NT (NE + NN)   // 1700000 edges incl. self-loops
#define DD 128
#define NB 500          // dst buckets
#define BR 200          // node range per bucket (NB*BR == NN)
#define BCAP 4096       // bucket capacity (mean 3200, sigma 56 -> 15.9 sigma headroom)
#define NCH 2048        // edges per k_bucket block
#define NBK 782         // ceil(NE/NCH)
#define NBG 1563        // ceil(NN/64) gemm blocks
#define PW 68           // padded LDS row stride in uints (64 + 4 -> 2-way banks only)
#define BMAGIC 21474837u // ceil(2^32/200); exact for d < 100000

typedef unsigned int uint;
typedef unsigned short ushort;
typedef __attribute__((ext_vector_type(8))) short bf16x8;
typedef __attribute__((ext_vector_type(4))) float f32x4;

// round-to-nearest-even fp32 -> bf16 (16-bit payload in a uint)
__device__ __forceinline__ uint bfr(float f){
  uint u = __float_as_uint(f);
  return (u + 0x7FFFu + ((u >> 16) & 1u)) >> 16;
}
__device__ __forceinline__ uint pk2(float a, float b){
  return (bfr(a) & 0xFFFFu) | (bfr(b) << 16);
}
__device__ __forceinline__ bf16x8 asbf(uint4 u){
  union { uint4 u; bf16x8 b; } c; c.u = u; return c.b;
}

// ---------------- K2: fused [Wt transpose (blocks 0,1) | bucket sort (782)] ----------------
__global__ __launch_bounds__(256) void k_pre1(const float* __restrict__ W1f, const float* __restrict__ W2f,
    uint* __restrict__ Wt1, uint* __restrict__ Wt2,
    const int* __restrict__ ei, int* __restrict__ gcnt, uint* __restrict__ bedge){
  __shared__ uint   ent[NCH];    // src(17b) | d_local(8b)<<17
  __shared__ ushort bbs[NCH];    // bucket id
  __shared__ int    hist[NB];
  __shared__ int    fl[NB];
  __shared__ int    gb[NB];
  int t = threadIdx.x;
  if (blockIdx.x < 2){
    const float* W = blockIdx.x ? W2f : W1f;
    uint* Wt = blockIdx.x ? Wt2 : Wt1;
    int n = t >> 1, k0 = (t & 1) * 64;
    for (int kk = 0; kk < 64; kk += 2){
      float v0 = W[(size_t)(k0+kk  )*DD + n];
      float v1 = W[(size_t)(k0+kk+1)*DD + n];
      Wt[(size_t)n*64 + ((k0+kk)>>1)] = pk2(v0, v1);
    }
    return;
  }
  int bid = blockIdx.x - 2;
  int base = bid * NCH;
  int nv = NE - base; if (nv > NCH) nv = NCH;
  for (int b = t; b < NB; b += 256){ hist[b] = 0; fl[b] = 0; }
  __syncthreads();
  for (int j = t; j < nv; j += 256){
    int i = base + j;                      // coalesced
    uint s = (uint)ei[i];
    uint d = (uint)ei[NE + i];
    uint b = __umulhi(d, BMAGIC);          // d / 200
    uint dl = d - b*BR;
    ent[j] = s | (dl << 17);
    bbs[j] = (ushort)b;
    atomicAdd(&hist[b], 1);
  }
  __syncthreads();
  for (int b = t; b < NB; b += 256){
    int h = hist[b];
    gb[b] = h ? atomicAdd(&gcnt[b*16], h) : 0;   // bulk reservation
  }
  __syncthreads();
  for (int j = t; j < nv; j += 256){
    uint b = bbs[j];
    int q = atomicAdd(&fl[b], 1);          // LDS fill
    bedge[(size_t)b*BCAP + gb[b] + q] = ent[j];
  }
}

// ---------------- K3: fused [bucket-total exclusive scan (block 0) | per-bucket degree->deg,dis (500)] ----------------
__global__ __launch_bounds__(256) void k_pre2(const int* __restrict__ gcnt, int* __restrict__ bbase,
    const uint* __restrict__ bedge, int* __restrict__ deg, float* __restrict__ dis){
  __shared__ int sm[256];
  int t = threadIdx.x;
  if (blockIdx.x == 0){
    // 2 buckets per thread: scan pair-sums, emit both exclusive offsets
    int i0 = 2*t, i1 = 2*t + 1;
    int v0 = (i0 < NB) ? (gcnt[i0*16] + BR) : 0;
    int v1 = (i1 < NB) ? (gcnt[i1*16] + BR) : 0;
    int p = v0 + v1;
    sm[t] = p;
    __syncthreads();
    for (int off = 1; off < 256; off <<= 1){
      int a = (t >= off) ? sm[t-off] : 0;
      __syncthreads();
      sm[t] += a;
      __syncthreads();
    }
    int excl = sm[t] - p;
    if (i0 < NB) bbase[i0] = excl;
    if (i1 < NB) bbase[i1] = excl + v0;
    return;
  }
  int b = blockIdx.x - 1;
  int* cl = sm;                            // BR <= 256
  if (t < BR) cl[t] = 0;
  __syncthreads();
  int cnt = gcnt[b*16];
  for (int e = t; e < cnt; e += 256){
    atomicAdd(&cl[bedge[(size_t)b*BCAP + e] >> 17], 1);
  }
  __syncthreads();
  if (t < BR){
    int n = b*BR + t;
    int dg = cl[t];
    deg[n] = dg;                           // in-degree excl self-loop
    dis[n] = rsqrtf((float)(dg + 1));
  }
}

// ---------------- shared GEMM body: Y[r] = bf16(dis[r] * (X@W)[r]) ----------------
// 64 rows/block. Staging coalesced into padded LDS (2-way banks only);
// fragments via ds_read_b128; lane (g,li): Wt row nt*16+li, X row wv*16+li,
// k-chunk ks*32+g*8. C/D: lane owns row r, cols nt*16+g*4+reg (HW-verified).
template<int IN_BF16>
__device__ __forceinline__ void gemm_body(uint* __restrict__ Ws, uint* __restrict__ Xs,
    const void* __restrict__ Xv, const uint* __restrict__ Wt,
    const float* __restrict__ dis, uint* __restrict__ Y, int row0){
  int t = threadIdx.x;
  // stage Wt: 2048 uint4, coalesced
  #pragma unroll
  for (int it = 0; it < 8; ++it){
    int f = it*256 + t;
    uint4 v = ((const uint4*)Wt)[f];
    int row = f >> 4, c4 = f & 15;
    *(uint4*)&Ws[row*PW + c4*4] = v;
  }
  // stage X tile (64 rows), coalesced; zero-fill invalid rows
  if (!IN_BF16){
    const float* X = (const float*)Xv;
    #pragma unroll
    for (int it = 0; it < 8; ++it){
      int f = it*256 + t;                  // 0..2047 float4
      int row = f >> 5, c4 = f & 31;
      int gr = row0 + row;
      float4 v = (gr < NN) ? ((const float4*)X)[(size_t)gr*32 + c4]
                           : make_float4(0.f,0.f,0.f,0.f);
      uint2 p; p.x = pk2(v.x, v.y); p.y = pk2(v.z, v.w);
      *(uint2*)&Xs[row*PW + c4*2] = p;
    }
  } else {
    const uint* X = (const uint*)Xv;
    #pragma unroll
    for (int it = 0; it < 4; ++it){
      int f = it*256 + t;                  // 0..1023 uint4
      int row = f >> 4, c4 = f & 15;
      int gr = row0 + row;
      uint4 v = (gr < NN) ? ((const uint4*)X)[(size_t)gr*16 + c4]
                          : make_uint4(0,0,0,0);
      *(uint4*)&Xs[row*PW + c4*4] = v;
    }
  }
  __syncthreads();

  int wv = t >> 6, l = t & 63;
  int g = l >> 4, li = l & 15;
  int rb = wv*16 + li;                    // row within block
  int r  = row0 + rb;
  f32x4 acc[8];
  #pragma unroll
  for (int i = 0; i < 8; ++i) acc[i] = (f32x4){0.f,0.f,0.f,0.f};

  #pragma unroll
  for (int ks = 0; ks < 4; ++ks){
    int c = (ks*4 + g)*4;                 // uint offset of this lane's k-chunk
    bf16x8 bfrag = asbf(*(const uint4*)&Xs[rb*PW + c]);
    #pragma unroll
    for (int nt = 0; nt < 8; ++nt){
      bf16x8 afrag = asbf(*(const uint4*)&Ws[(nt*16 + li)*PW + c]);
      acc[nt] = __builtin_amdgcn_mfma_f32_16x16x32_bf16(afrag, bfrag, acc[nt], 0, 0, 0);
    }
  }
  if (r < NN){
    float dr = dis[r];
    #pragma unroll
    for (int nt = 0; nt < 8; ++nt){
      uint2 o;
      o.x = pk2(acc[nt][0]*dr, acc[nt][1]*dr);
      o.y = pk2(acc[nt][2]*dr, acc[nt][3]*dr);
      *(uint2*)&Y[(size_t)r*64 + nt*8 + g*2] = o;   // row-major packed
    }
  }
}

// ---------------- K4: fused [CSR build (blocks 0..499) | layer-1 GEMM (500..2062)] ----------------
// Build and gemm1 are independent after k_pre2 -> co-resident heterogeneous work.
// Build's LDS aliases the gemm's 52.2KB buffer (disjoint branches) -> 3 blocks/CU.
__global__ __launch_bounds__(256, 3) void k_bg(const int* __restrict__ gcnt,
    const int* __restrict__ bbase, const uint* __restrict__ bedge,
    const int* __restrict__ deg, const float* __restrict__ dis,
    int* __restrict__ rowptr, uint* __restrict__ es,
    const float* __restrict__ X, const uint* __restrict__ Wt1, uint* __restrict__ H){
  __shared__ uint smem[192*PW];           // gemm: Ws|Xs ; build: cl|fl|pf
  int t = threadIdx.x;
  if (blockIdx.x >= NB){
    gemm_body<0>(smem, smem + 128*PW, X, Wt1, dis, H, (blockIdx.x - NB)*64);
    return;
  }
  int b = blockIdx.x;
  int base = bbase[b];
  int* cl = (int*)smem;
  int* fl = cl + BR;
  int* pf = cl + 2*BR;                    // 256 ints
  if (t < BR){ cl[t] = deg[b*BR + t]; fl[t] = 0; }
  __syncthreads();
  // inclusive scan over (cl[i]+1)
  int v = (t < BR) ? (cl[t] + 1) : 0;
  pf[t] = v;
  __syncthreads();
  for (int off = 1; off < 256; off <<= 1){
    int a = (t >= off) ? pf[t-off] : 0;
    __syncthreads();
    pf[t] += a;
    __syncthreads();
  }
  if (t < BR){
    int n  = b*BR + t;
    int p0 = base + pf[t] - v;             // exclusive prefix (globally monotone)
    rowptr[n] = p0;
    es[p0 + cl[t]] = (uint)n;              // self-loop last
  }
  if (b == NB-1 && t == 0) rowptr[NN] = NT;
  __syncthreads();
  int cnt = gcnt[b*16];
  for (int e = t; e < cnt; e += 256){
    uint u = bedge[(size_t)b*BCAP + e];
    int  dloc = u >> 17;
    int  q  = atomicAdd(&fl[dloc], 1);
    int  p0 = base + pf[dloc] - (cl[dloc] + 1);
    es[p0 + q] = u & 0x1FFFFu;
  }
}

// ---------------- layer-2 GEMM (bf16 input) ----------------
__global__ __launch_bounds__(256, 3) void k_gemm2(const uint* __restrict__ X,
    const uint* __restrict__ Wt, const float* __restrict__ dis, uint* __restrict__ Y){
  __shared__ uint smem[192*PW];
  gemm_body<1>(smem, smem + 128*PW, X, Wt, dis, Y, blockIdx.x*64);
}

// ---------------- CSR aggregation + bias + ELU (flat, R9-proven) ----------------
// out[n] = elu(dis[n] * sum_{s in N(n)} H'[s] + b); H' rows pre-scaled by dis[s].
// one WAVE per node (4 nodes / 256-thread block); lane = bf16 channel pair;
// 16x edge unroll -> 16 gathers in flight per wave.
template<int OUT_BF16>
__global__ __launch_bounds__(256) void k_agg(const uint* __restrict__ H,
    const int* __restrict__ rowptr, const float* __restrict__ dis,
    const uint* __restrict__ es, const float* __restrict__ bias,
    void* __restrict__ outv){
  int wid  = threadIdx.x >> 6;
  int lane = threadIdx.x & 63;
  int n = blockIdx.x*4 + wid;            // grid*4 == NN exactly
  int e0 = rowptr[n];
  int e1 = rowptr[n+1];
  float a0 = 0.f, a1 = 0.f, a2 = 0.f, a3 = 0.f;
  int e = e0;

#define ASTEP(k,A,B) { uint s##k = es[e+k]; \
    uint h##k = H[(size_t)s##k*64 + lane]; \
    A += __uint_as_float(h##k << 16); \
    B += __uint_as_float(h##k & 0xFFFF0000u); }

  for (; e + 16 <= e1; e += 16){
    ASTEP( 0,a0,a1) ASTEP( 1,a2,a3) ASTEP( 2,a0,a1) ASTEP( 3,a2,a3)
    ASTEP( 4,a0,a1) ASTEP( 5,a2,a3) ASTEP( 6,a0,a1) ASTEP( 7,a2,a3)
    ASTEP( 8,a0,a1) ASTEP( 9,a2,a3) ASTEP(10,a0,a1) ASTEP(11,a2,a3)
    ASTEP(12,a0,a1) ASTEP(13,a2,a3) ASTEP(14,a0,a1) ASTEP(15,a2,a3)
  }
  for (; e + 4 <= e1; e += 4){
    ASTEP(0,a0,a1) ASTEP(1,a2,a3) ASTEP(2,a0,a1) ASTEP(3,a2,a3)
  }
  for (; e < e1; ++e){
    ASTEP(0,a0,a1)
  }
#undef ASTEP

  float dn = dis[n];
  float2 b = *(const float2*)&bias[lane*2];
  float v0 = fmaf(dn, a0 + a2, b.x);
  float v1 = fmaf(dn, a1 + a3, b.y);
  v0 = (v0 > 0.f) ? v0 : expm1f(v0);
  v1 = (v1 > 0.f) ? v1 : expm1f(v1);
  if (OUT_BF16){
    ((uint*)outv)[(size_t)n*64 + lane] = pk2(v0, v1);
  } else {
    float2 o; o.x = v0; o.y = v1;
    *(float2*)&((float*)outv)[(size_t)n*DD + lane*2] = o;
  }
}

// ---------------- launch ----------------

extern "C" void kernel_launch(void* const* d_in, const int* in_sizes, int n_in,
                              void* d_out, int out_size, void* d_ws, size_t ws_size,
                              hipStream_t stream){
  const float* x  = (const float*)d_in[0];
  const int*   ei = (const int*)d_in[1];   // [2, NE]: src row then dst row
  const float* W1 = (const float*)d_in[2];
  const float* b1 = (const float*)d_in[3];
  const float* W2 = (const float*)d_in[4];
  const float* b2 = (const float*)d_in[5];

  // workspace carve-up (int units), every region 64-int (256B) aligned.
  // H alignment is CRITICAL (misaligned 256B rows -> +42% gather FETCH, R4..R8).
  // out1 = FULL 6.4M uints (R11 lesson); aliases bedge (dead after k_bg's
  // build blocks) -- safe: agg<1> (only out1 writer) runs after k_bg.
  // H2 = H (H dead after agg<1>).
  int*   ws_i   = (int*)d_ws;
  int*   gcnt   = ws_i + 0;                 // [0, 8000)  500*16 padded counters
  int*   bbase  = ws_i + 8000;              // [8000, 8576)
  float* dis    = (float*)(ws_i + 8576);    // [8576, 108608)
  int*   rowptr = ws_i + 108608;            // [108608, 208704)  100001 used
  int*   deg    = ws_i + 208704;            // [208704, 308736)  100000 used
  uint*  Wt1    = (uint*)(ws_i + 308736);   // [308736, 316928)  128x128 bf16
  uint*  Wt2    = (uint*)(ws_i + 316928);   // [316928, 325120)
  uint*  es     = (uint*)(ws_i + 325120);   // [325120, 2025152)  1700000 used
  uint*  bedge  = (uint*)(ws_i + 2025152);  // [2025152, 4073152)  dead after k_bg
  uint*  out1   = (uint*)(ws_i + 2025152);  // [2025152, 8425152)  6.4M uints, %256==0
  uint*  H      = (uint*)(ws_i + 8425152);  // [8425152, 14825152) 6.4M uints, %256==0
  uint*  H2     = H;                        //   reused: H dead after agg<1>
  // total 14825152 ints = 59.3 MB (<= 66.4 MB proven in R1)

  hipMemsetAsync(gcnt, 0, 8000*sizeof(int), stream);

  // K2: [Wt transpose | bucket sort]
  k_pre1<<<NBK + 2, 256, 0, stream>>>(W1, W2, Wt1, Wt2, ei, gcnt, bedge);
  // K3: [bucket-total scan | degree histogram -> deg, dis]
  k_pre2<<<NB + 1,  256, 0, stream>>>(gcnt, bbase, bedge, deg, dis);
  // K4: [CSR build | layer-1 GEMM: H = bf16(dis*(x@W1))]  (independent halves)
  k_bg  <<<NB + NBG,256, 0, stream>>>(gcnt, bbase, bedge, deg, dis, rowptr, es, x, Wt1, H);
  // layer-1 agg: out1 = bf16(elu(dis*agg(H) + b1))
  k_agg<1><<<25000, 256, 0, stream>>>(H, rowptr, dis, es, b1, out1);
  // layer-2 GEMM: H2 = bf16(dis*(out1@W2))
  k_gemm2 <<<NBG,   256, 0, stream>>>(out1, Wt2, dis, H2);
  // layer-2 agg: out = elu(dis*agg(H2) + b2)
  k_agg<0><<<25000, 256, 0, stream>>>(H2, rowptr, dis, es, b2, d_out);
}